// Round 1
// baseline (320.639 us; speedup 1.0000x reference)
//
#include <hip/hip_runtime.h>

#define D 128

// ---------- bf16 helpers (manual, RNE) ----------
static __device__ __forceinline__ unsigned short f2bf(float f) {
    unsigned int u = __float_as_uint(f);
    u += 0x7fffu + ((u >> 16) & 1u);
    return (unsigned short)(u >> 16);
}
static __device__ __forceinline__ float bf_lo(unsigned int v) {
    return __uint_as_float(v << 16);
}
static __device__ __forceinline__ float bf_hi(unsigned int v) {
    return __uint_as_float(v & 0xffff0000u);
}

// ---------- GEMM: h = x @ W, store h as packed bf16 pairs ----------
static __device__ __forceinline__ void fma_row(float4& a, float4 xv,
                                               float4 w0, float4 w1,
                                               float4 w2, float4 w3) {
    a.x = fmaf(xv.x, w0.x, a.x); a.x = fmaf(xv.y, w1.x, a.x);
    a.x = fmaf(xv.z, w2.x, a.x); a.x = fmaf(xv.w, w3.x, a.x);
    a.y = fmaf(xv.x, w0.y, a.y); a.y = fmaf(xv.y, w1.y, a.y);
    a.y = fmaf(xv.z, w2.y, a.y); a.y = fmaf(xv.w, w3.y, a.y);
    a.z = fmaf(xv.x, w0.z, a.z); a.z = fmaf(xv.y, w1.z, a.z);
    a.z = fmaf(xv.z, w2.z, a.z); a.z = fmaf(xv.w, w3.z, a.z);
    a.w = fmaf(xv.x, w0.w, a.w); a.w = fmaf(xv.y, w1.w, a.w);
    a.w = fmaf(xv.z, w2.w, a.w); a.w = fmaf(xv.w, w3.w, a.w);
}

__global__ __launch_bounds__(256) void gemm_k(const float* __restrict__ x,
                                              const float* __restrict__ W,
                                              unsigned int* __restrict__ h2,
                                              int N) {
    __shared__ float Wl[D * D];  // 64 KB
    int t = threadIdx.x;
    // stage W into LDS: 4096 float4 / 256 threads = 16 each, coalesced
    {
        const float4* Wv = (const float4*)W;
        float4* Wlv = (float4*)Wl;
#pragma unroll
        for (int i = 0; i < 16; ++i) Wlv[t + 256 * i] = Wv[t + 256 * i];
    }
    __syncthreads();

    int row0 = blockIdx.x * 64 + (t >> 5) * 8;  // 8 rows per thread
    int cg = (t & 31) * 4;                      // 4 consecutive cols
    float4 acc[8];
#pragma unroll
    for (int r = 0; r < 8; ++r) acc[r] = make_float4(0.f, 0.f, 0.f, 0.f);

    for (int k = 0; k < D; k += 4) {
        float4 w0 = *(const float4*)&Wl[(k + 0) * D + cg];
        float4 w1 = *(const float4*)&Wl[(k + 1) * D + cg];
        float4 w2 = *(const float4*)&Wl[(k + 2) * D + cg];
        float4 w3 = *(const float4*)&Wl[(k + 3) * D + cg];
#pragma unroll
        for (int r = 0; r < 8; ++r) {
            int row = row0 + r;
            float4 xv = make_float4(0.f, 0.f, 0.f, 0.f);
            if (row < N) xv = *(const float4*)&x[(size_t)row * D + k];
            fma_row(acc[r], xv, w0, w1, w2, w3);
        }
    }
#pragma unroll
    for (int r = 0; r < 8; ++r) {
        int row = row0 + r;
        if (row < N) {
            unsigned int p0 = ((unsigned int)f2bf(acc[r].y) << 16) | f2bf(acc[r].x);
            unsigned int p1 = ((unsigned int)f2bf(acc[r].w) << 16) | f2bf(acc[r].z);
            *(uint2*)&h2[(size_t)row * 64 + (cg >> 1)] = make_uint2(p0, p1);
        }
    }
}

// ---------- degree count over dst ----------
__global__ void count_k(const int* __restrict__ ei, int* __restrict__ cnt, int E) {
    int e = blockIdx.x * blockDim.x + threadIdx.x;
    if (e < E) atomicAdd(&cnt[ei[E + e]], 1);
}

// ---------- dinv = rsqrt(deg), deg = cnt + 1 (self loop) ----------
__global__ void dinv_k(const int* __restrict__ cnt, float* __restrict__ dinv, int N) {
    int i = blockIdx.x * blockDim.x + threadIdx.x;
    if (i < N) dinv[i] = rsqrtf((float)cnt[i] + 1.0f);
}

// ---------- 3-phase exclusive scan of cnt -> rowstart ----------
__global__ __launch_bounds__(256) void scan_a(const int* __restrict__ cnt,
                                              int* __restrict__ rowstart,
                                              int* __restrict__ bsum, int N) {
    __shared__ int sh[256];
    int t = threadIdx.x;
    int base = blockIdx.x * 1024 + t * 4;
    int v[4];
#pragma unroll
    for (int j = 0; j < 4; ++j) v[j] = (base + j < N) ? cnt[base + j] : 0;
    int ts = v[0] + v[1] + v[2] + v[3];
    sh[t] = ts;
    __syncthreads();
    for (int off = 1; off < 256; off <<= 1) {
        int u = (t >= off) ? sh[t - off] : 0;
        __syncthreads();
        sh[t] += u;
        __syncthreads();
    }
    int run = sh[t] - ts;  // exclusive prefix of this thread's chunk
#pragma unroll
    for (int j = 0; j < 4; ++j) {
        if (base + j < N) rowstart[base + j] = run;
        run += v[j];
    }
    if (t == 255) bsum[blockIdx.x] = sh[255];
}

__global__ void scan_b(const int* __restrict__ bsum, int* __restrict__ boff,
                       int nb, int* __restrict__ rowstart, int N) {
    __shared__ int sh[128];
    int t = threadIdx.x;
    int v = (t < nb) ? bsum[t] : 0;
    sh[t] = v;
    __syncthreads();
    for (int off = 1; off < 128; off <<= 1) {
        int u = (t >= off) ? sh[t - off] : 0;
        __syncthreads();
        sh[t] += u;
        __syncthreads();
    }
    if (t < nb) boff[t] = sh[t] - v;
    if (t == 127) rowstart[N] = sh[127];  // total = E
}

__global__ void scan_c(int* __restrict__ rowstart, const int* __restrict__ boff, int N) {
    int i = blockIdx.x * blockDim.x + threadIdx.x;
    if (i < N) rowstart[i] += boff[i >> 10];
}

// ---------- fill CSR edge lists (src per dst) ----------
__global__ void fill_k(const int* __restrict__ ei, const int* __restrict__ rowstart,
                       int* __restrict__ cursor, int* __restrict__ eidx, int E) {
    int e = blockIdx.x * blockDim.x + threadIdx.x;
    if (e < E) {
        int s = ei[e];
        int d = ei[E + e];
        int p = atomicAdd(&cursor[d], 1);
        eidx[rowstart[d] + p] = s;
    }
}

// ---------- pull-mode aggregate + bias + relu + residual (fused) ----------
__global__ __launch_bounds__(256) void agg_k(const unsigned int* __restrict__ h2,
                                             const float* __restrict__ x,
                                             const float* __restrict__ b,
                                             const float* __restrict__ dinv,
                                             const int* __restrict__ rowstart,
                                             const int* __restrict__ eidx,
                                             float* __restrict__ out, int N) {
    int w = threadIdx.x >> 6;
    int lane = threadIdx.x & 63;
    int i = blockIdx.x * 4 + w;
    if (i >= N) return;

    float di = dinv[i];
    int rs = rowstart[i];
    int re = rowstart[i + 1];
    float a0 = 0.f, a1 = 0.f;
    for (int j = rs; j < re; ++j) {
        int s = eidx[j];
        float nr = dinv[s] * di;
        unsigned int hv = h2[(size_t)s * 64 + lane];
        a0 = fmaf(bf_lo(hv), nr, a0);
        a1 = fmaf(bf_hi(hv), nr, a1);
    }
    {   // self loop
        float nr = di * di;
        unsigned int hv = h2[(size_t)i * 64 + lane];
        a0 = fmaf(bf_lo(hv), nr, a0);
        a1 = fmaf(bf_hi(hv), nr, a1);
    }
    float2 bb = *(const float2*)&b[2 * lane];
    float2 xx = *(const float2*)&x[(size_t)i * D + 2 * lane];
    float o0 = xx.x + fmaxf(a0 + bb.x, 0.f);
    float o1 = xx.y + fmaxf(a1 + bb.y, 0.f);
    *(float2*)&out[(size_t)i * D + 2 * lane] = make_float2(o0, o1);
}

extern "C" void kernel_launch(void* const* d_in, const int* in_sizes, int n_in,
                              void* d_out, int out_size, void* d_ws, size_t ws_size,
                              hipStream_t stream) {
    const float* x = (const float*)d_in[0];
    const int* ei = (const int*)d_in[1];   // harness converts integer inputs to int32
    const float* W = (const float*)d_in[2];
    const float* b = (const float*)d_in[3];
    float* out = (float*)d_out;

    int N = in_sizes[0] / D;
    int E = in_sizes[1] / 2;

    char* ws = (char*)d_ws;
    float* dinv        = (float*)(ws + 0);
    int* cnt           = (int*)(ws + (512 << 10));
    int* rowstart      = (int*)(ws + (1024 << 10));
    int* cursor        = (int*)(ws + (1536 << 10));
    int* bsum          = (int*)(ws + (2048 << 10));
    int* boff          = (int*)(ws + (2048 << 10) + 4096);
    int* eidx          = (int*)(ws + (2056 << 10));            // E*4 = 2.44 MB
    unsigned int* h2   = (unsigned int*)(ws + (4608 << 10));   // N*64*4 = 24.4 MB

    hipMemsetAsync(cnt, 0, (size_t)N * 4, stream);
    hipMemsetAsync(cursor, 0, (size_t)N * 4, stream);

    gemm_k<<<(N + 63) / 64, 256, 0, stream>>>(x, W, h2, N);
    count_k<<<(E + 255) / 256, 256, 0, stream>>>(ei, cnt, E);
    dinv_k<<<(N + 255) / 256, 256, 0, stream>>>(cnt, dinv, N);
    int nb = (N + 1023) / 1024;
    scan_a<<<nb, 256, 0, stream>>>(cnt, rowstart, bsum, N);
    scan_b<<<1, 128, 0, stream>>>(bsum, boff, nb, rowstart, N);
    scan_c<<<(N + 255) / 256, 256, 0, stream>>>(rowstart, boff, N);
    fill_k<<<(E + 255) / 256, 256, 0, stream>>>(ei, rowstart, cursor, eidx, E);
    agg_k<<<(N + 3) / 4, 256, 0, stream>>>(h2, x, b, dinv, rowstart, eidx, out, N);
}

// Round 2
// 151.360 us; speedup vs baseline: 2.1184x; 2.1184x over previous
//
#include <hip/hip_runtime.h>

#define D 128

typedef __attribute__((ext_vector_type(8))) short short8;
typedef __attribute__((ext_vector_type(4))) float f32x4;

// ---------- bf16 helpers (manual, RNE) ----------
static __device__ __forceinline__ unsigned short f2bf(float f) {
    unsigned int u = __float_as_uint(f);
    u += 0x7fffu + ((u >> 16) & 1u);
    return (unsigned short)(u >> 16);
}
static __device__ __forceinline__ float bf_lo(unsigned int v) {
    return __uint_as_float(v << 16);
}
static __device__ __forceinline__ float bf_hi(unsigned int v) {
    return __uint_as_float(v & 0xffff0000u);
}

// ---------- MFMA GEMM: hs = (x @ W) * dinv[row], stored bf16 ----------
// A frag (16x32): lane l holds x[row0 + (l&15)][kk*32 + (l>>4)*8 + j], j=0..7
// B frag (32x16): lane l holds W[kk*32 + (l>>4)*8 + j][nt*16 + (l&15)]
// D (16x16):      lane l holds h[row0 + (l>>4)*4 + j][nt*16 + (l&15)]
__global__ __launch_bounds__(256) void gemm_mfma(const float* __restrict__ x,
                                                 const float* __restrict__ W,
                                                 const float* __restrict__ dinv,
                                                 unsigned short* __restrict__ h,
                                                 int N) {
    __shared__ unsigned short Wt[D * D];       // transposed W, bf16, XOR-swizzled (32 KB)
    __shared__ unsigned short ost[4][16 * D];  // per-wave output stage (16 KB)

    int t = threadIdx.x;
    int w = t >> 6, l = t & 63;
    int mrow = l & 15, kgrp = l >> 4;

    // ---- stage Wt[c][k] = bf16(W[k][c]), swizzled: byte ^= (c&7)<<4 ----
    {
        const float4* Wv = (const float4*)W;
        for (int i = 0; i < 16; ++i) {
            int idx = i * 256 + t;       // 4096 float4 total
            int k = idx >> 5;            // W row
            int c0 = (idx & 31) * 4;     // W col
            float4 v = Wv[idx];
            float vv[4] = {v.x, v.y, v.z, v.w};
#pragma unroll
            for (int j = 0; j < 4; ++j) {
                int c = c0 + j;
                unsigned int B = (unsigned int)c * 256 + (unsigned int)k * 2;
                unsigned int sB = B ^ (((unsigned int)c & 7u) << 4);
                *(unsigned short*)((char*)Wt + sB) = f2bf(vv[j]);
            }
        }
    }
    __syncthreads();

    for (int rt = 0; rt < 4; ++rt) {
        int row0 = blockIdx.x * 256 + w * 64 + rt * 16;  // N % 16 == 0
        bool act = row0 < N;

        f32x4 acc[8];
        if (act) {
            // A fragments: 8 consecutive floats per lane per kk
            short8 a[4];
#pragma unroll
            for (int kk = 0; kk < 4; ++kk) {
                const float* p = &x[(size_t)(row0 + mrow) * D + kk * 32 + kgrp * 8];
                float4 q0 = *(const float4*)p;
                float4 q1 = *(const float4*)(p + 4);
                short8 af;
                af[0] = (short)f2bf(q0.x); af[1] = (short)f2bf(q0.y);
                af[2] = (short)f2bf(q0.z); af[3] = (short)f2bf(q0.w);
                af[4] = (short)f2bf(q1.x); af[5] = (short)f2bf(q1.y);
                af[6] = (short)f2bf(q1.z); af[7] = (short)f2bf(q1.w);
                a[kk] = af;
            }
#pragma unroll
            for (int nt = 0; nt < 8; ++nt) {
                acc[nt] = (f32x4){0.f, 0.f, 0.f, 0.f};
#pragma unroll
                for (int kk = 0; kk < 4; ++kk) {
                    unsigned int c = nt * 16 + mrow;
                    unsigned int B = c * 256 + (unsigned int)(kk * 32 + kgrp * 8) * 2;
                    unsigned int sB = B ^ ((c & 7u) << 4);
                    short8 bf = *(const short8*)((char*)Wt + sB);
                    acc[nt] = __builtin_amdgcn_mfma_f32_16x16x32_bf16(a[kk], bf, acc[nt], 0, 0, 0);
                }
            }
            // epilogue: scale by dinv[row], cvt bf16, stage to LDS
            float dv[4];
#pragma unroll
            for (int j = 0; j < 4; ++j) dv[j] = dinv[row0 + kgrp * 4 + j];
#pragma unroll
            for (int nt = 0; nt < 8; ++nt)
#pragma unroll
                for (int j = 0; j < 4; ++j) {
                    int rr = kgrp * 4 + j;
                    ost[w][rr * D + nt * 16 + mrow] = f2bf(acc[nt][j] * dv[j]);
                }
        }
        __syncthreads();
        if (act) {
            // coalesced readback + 16B global stores (16 rows x 256B = 256 uint4)
            const uint4* os4 = (const uint4*)ost[w];
            uint4* H4 = (uint4*)h;
#pragma unroll
            for (int i2 = 0; i2 < 4; ++i2) {
                int e = i2 * 64 + l;
                H4[(size_t)row0 * 16 + e] = os4[e];
            }
        }
        __syncthreads();
    }
}

// ---------- degree count over dst ----------
__global__ void count_k(const int* __restrict__ ei, int* __restrict__ cnt, int E) {
    int e = blockIdx.x * blockDim.x + threadIdx.x;
    if (e < E) atomicAdd(&cnt[ei[E + e]], 1);
}

// ---------- dinv = rsqrt(deg), deg = cnt + 1 (self loop) ----------
__global__ void dinv_k(const int* __restrict__ cnt, float* __restrict__ dinv, int N) {
    int i = blockIdx.x * blockDim.x + threadIdx.x;
    if (i < N) dinv[i] = rsqrtf((float)cnt[i] + 1.0f);
}

// ---------- 3-phase exclusive scan of cnt -> rowstart ----------
__global__ __launch_bounds__(256) void scan_a(const int* __restrict__ cnt,
                                              int* __restrict__ rowstart,
                                              int* __restrict__ bsum, int N) {
    __shared__ int sh[256];
    int t = threadIdx.x;
    int base = blockIdx.x * 1024 + t * 4;
    int v[4];
#pragma unroll
    for (int j = 0; j < 4; ++j) v[j] = (base + j < N) ? cnt[base + j] : 0;
    int ts = v[0] + v[1] + v[2] + v[3];
    sh[t] = ts;
    __syncthreads();
    for (int off = 1; off < 256; off <<= 1) {
        int u = (t >= off) ? sh[t - off] : 0;
        __syncthreads();
        sh[t] += u;
        __syncthreads();
    }
    int run = sh[t] - ts;
#pragma unroll
    for (int j = 0; j < 4; ++j) {
        if (base + j < N) rowstart[base + j] = run;
        run += v[j];
    }
    if (t == 255) bsum[blockIdx.x] = sh[255];
}

__global__ void scan_b(const int* __restrict__ bsum, int* __restrict__ boff,
                       int nb, int* __restrict__ rowstart, int N) {
    __shared__ int sh[128];
    int t = threadIdx.x;
    int v = (t < nb) ? bsum[t] : 0;
    sh[t] = v;
    __syncthreads();
    for (int off = 1; off < 128; off <<= 1) {
        int u = (t >= off) ? sh[t - off] : 0;
        __syncthreads();
        sh[t] += u;
        __syncthreads();
    }
    if (t < nb) boff[t] = sh[t] - v;
    if (t == 127) rowstart[N] = sh[127];
}

__global__ void scan_c(int* __restrict__ rowstart, const int* __restrict__ boff, int N) {
    int i = blockIdx.x * blockDim.x + threadIdx.x;
    if (i < N) rowstart[i] += boff[i >> 10];
}

// ---------- fill CSR edge lists (src per dst) ----------
__global__ void fill_k(const int* __restrict__ ei, const int* __restrict__ rowstart,
                       int* __restrict__ cursor, int* __restrict__ eidx, int E) {
    int e = blockIdx.x * blockDim.x + threadIdx.x;
    if (e < E) {
        int s = ei[e];
        int d = ei[E + e];
        int p = atomicAdd(&cursor[d], 1);
        eidx[rowstart[d] + p] = s;
    }
}

// ---------- pull-mode aggregate + bias + relu + residual (fused) ----------
// hs rows are pre-scaled by dinv[src]; agg = di * (hs[i] + sum hs[src])
__global__ __launch_bounds__(256) void agg_k(const unsigned int* __restrict__ h2,
                                             const float* __restrict__ x,
                                             const float* __restrict__ b,
                                             const float* __restrict__ dinv,
                                             const int* __restrict__ rowstart,
                                             const int* __restrict__ eidx,
                                             float* __restrict__ out, int N) {
    int w = threadIdx.x >> 6;
    int lane = threadIdx.x & 63;
    int i = blockIdx.x * 4 + w;
    if (i >= N) return;

    float di = dinv[i];
    int rs = rowstart[i];
    int re = rowstart[i + 1];

    // self loop term (hs[i] * di == h[i]*di^2 after final scale)
    unsigned int hv = h2[(size_t)i * 64 + lane];
    float a0 = bf_lo(hv), a1 = bf_hi(hv);

    int j = rs;
    for (; j + 4 <= re; j += 4) {
        int s0 = eidx[j], s1 = eidx[j + 1], s2 = eidx[j + 2], s3 = eidx[j + 3];
        unsigned int v0 = h2[(size_t)s0 * 64 + lane];
        unsigned int v1 = h2[(size_t)s1 * 64 + lane];
        unsigned int v2 = h2[(size_t)s2 * 64 + lane];
        unsigned int v3 = h2[(size_t)s3 * 64 + lane];
        a0 += (bf_lo(v0) + bf_lo(v1)) + (bf_lo(v2) + bf_lo(v3));
        a1 += (bf_hi(v0) + bf_hi(v1)) + (bf_hi(v2) + bf_hi(v3));
    }
    for (; j < re; ++j) {
        unsigned int v0 = h2[(size_t)eidx[j] * 64 + lane];
        a0 += bf_lo(v0);
        a1 += bf_hi(v0);
    }
    a0 *= di;
    a1 *= di;

    float2 bb = *(const float2*)&b[2 * lane];
    float2 xx = *(const float2*)&x[(size_t)i * D + 2 * lane];
    float o0 = xx.x + fmaxf(a0 + bb.x, 0.f);
    float o1 = xx.y + fmaxf(a1 + bb.y, 0.f);
    *(float2*)&out[(size_t)i * D + 2 * lane] = make_float2(o0, o1);
}

extern "C" void kernel_launch(void* const* d_in, const int* in_sizes, int n_in,
                              void* d_out, int out_size, void* d_ws, size_t ws_size,
                              hipStream_t stream) {
    const float* x = (const float*)d_in[0];
    const int* ei = (const int*)d_in[1];
    const float* W = (const float*)d_in[2];
    const float* b = (const float*)d_in[3];
    float* out = (float*)d_out;

    int N = in_sizes[0] / D;
    int E = in_sizes[1] / 2;

    char* ws = (char*)d_ws;
    float* dinv      = (float*)(ws + 0);
    int* cnt         = (int*)(ws + (512 << 10));
    int* rowstart    = (int*)(ws + (1024 << 10));
    int* cursor      = (int*)(ws + (1536 << 10));
    int* bsum        = (int*)(ws + (2048 << 10));
    int* boff        = (int*)(ws + (2048 << 10) + 4096);
    int* eidx        = (int*)(ws + (2056 << 10));             // E*4 = 2.44 MB
    unsigned short* h = (unsigned short*)(ws + (4608 << 10)); // N*128*2 = 24.4 MB
    unsigned int* h2 = (unsigned int*)h;                      // same memory, pair view

    hipMemsetAsync(cnt, 0, (size_t)N * 4, stream);
    hipMemsetAsync(cursor, 0, (size_t)N * 4, stream);

    count_k<<<(E + 255) / 256, 256, 0, stream>>>(ei, cnt, E);
    dinv_k<<<(N + 255) / 256, 256, 0, stream>>>(cnt, dinv, N);
    gemm_mfma<<<(N + 255) / 256, 256, 0, stream>>>(x, W, dinv, h, N);
    int nb = (N + 1023) / 1024;
    scan_a<<<nb, 256, 0, stream>>>(cnt, rowstart, bsum, N);
    scan_b<<<1, 128, 0, stream>>>(bsum, boff, nb, rowstart, N);
    scan_c<<<(N + 255) / 256, 256, 0, stream>>>(rowstart, boff, N);
    fill_k<<<(E + 255) / 256, 256, 0, stream>>>(ei, rowstart, cursor, eidx, E);
    agg_k<<<(N + 3) / 4, 256, 0, stream>>>(h2, x, b, dinv, rowstart, eidx, out, N);
}